// Round 4
// baseline (193.255 us; speedup 1.0000x reference)
//
#include <hip/hip_runtime.h>

#define N_INPUTS 16384
#define N_DET    65536
#define KD       32
#define BATCH    32
#define SLICES   16                        // det slices; slice -> fixed XCD
#define DPB      (N_DET / SLICES)          // 4096 detectors per block
#define THREADS  1024                      // 16 waves, 1 block/CU (132 KB LDS)

__device__ __forceinline__ float max3f(float a, float b, float c) {
    return fmaxf(fmaxf(a, b), c);          // fuses to v_max3_f32
}

// keep even bits of a 32-bit word -> 16-bit compaction
__device__ __forceinline__ unsigned compact_even(unsigned v) {
    v &= 0x55555555u;
    v = (v | (v >> 1)) & 0x33333333u;
    v = (v | (v >> 2)) & 0x0F0F0F0Fu;
    v = (v | (v >> 4)) & 0x00FF00FFu;
    v = (v | (v >> 8)) & 0x0000FFFFu;
    return v;
}

// ---------------------------------------------------------------------------
// Round-0 structure + explicit software pipeline. Occupancy is LDS-pinned at
// 1 block/CU (4 waves/SIMD) no matter what, so VGPRs are free: prefetch ALL
// four detectors' id rows up front (32 independent dwordx4 -> latency hidden),
// then ping-pong gather/compute so detector j+1's 32-deep ds_read_b64 burst
// is in flight while detector j's max tree + winner chain + scatter runs.
// All array indices are compile-time (static vA/vB ping-pong, full unrolls)
// so everything stays in registers (no scratch).
// ---------------------------------------------------------------------------
__global__ __launch_bounds__(THREADS, 1) void inhibit(const float* __restrict__ x,
                                                      const int* __restrict__ det,
                                                      unsigned long long* __restrict__ pm) {
    __shared__ float2   xs[N_INPUTS];        // 128 KB: [id] -> (x_b0, x_b1)
    __shared__ unsigned fl[N_INPUTS / 16];   // 4 KB: bit 2p = b0-loser, 2p+1 = b1

    const int slice = blockIdx.x;
    const int pair  = blockIdx.y;
    const int tid   = threadIdx.x;

    fl[tid] = 0u;                            // 1024 words / 1024 threads

    // stage both rows interleaved: xs[i] = (x[b0][i], x[b1][i])
    const float4* x0 = (const float4*)(x + (size_t)(2 * pair) * N_INPUTS);
    const float4* x1 = (const float4*)(x + (size_t)(2 * pair + 1) * N_INPUTS);
    float4* xs4 = (float4*)xs;
#pragma unroll
    for (int k = 0; k < N_INPUTS / 4 / THREADS; ++k) {
        int t = tid + k * THREADS;
        float4 a = x0[t], b = x1[t];
        xs4[2 * t + 0] = make_float4(a.x, b.x, a.y, b.y);
        xs4[2 * t + 1] = make_float4(a.z, b.z, a.w, b.w);
    }
    __syncthreads();

    // ---- prefetch all 4 detectors' id rows (32 independent dwordx4) ----
    const int4* det4 = (const int4*)det;
    int ids[4][KD];
#pragma unroll
    for (int j = 0; j < 4; ++j) {
        const int4* drow = det4 + (size_t)(slice * DPB + j * THREADS + tid) * 8;
#pragma unroll
        for (int q = 0; q < 8; ++q) {
            int4 r = drow[q];
            ids[j][4 * q + 0] = r.x; ids[j][4 * q + 1] = r.y;
            ids[j][4 * q + 2] = r.z; ids[j][4 * q + 3] = r.w;
        }
    }

    float2 vA[KD], vB[KD];

#define GATHER(vbuf, J)                                                        \
    _Pragma("unroll") for (int s = 0; s < KD; ++s) vbuf[s] = xs[ids[J][s]];

#define COMPUTE(v, J)                                                          \
    {                                                                          \
        float t0[11], t1[11];                                                  \
        _Pragma("unroll") for (int i = 0; i < 10; ++i) {                       \
            t0[i] = max3f(v[3 * i].x, v[3 * i + 1].x, v[3 * i + 2].x);         \
            t1[i] = max3f(v[3 * i].y, v[3 * i + 1].y, v[3 * i + 2].y);         \
        }                                                                      \
        t0[10] = fmaxf(v[30].x, v[31].x);                                      \
        t1[10] = fmaxf(v[30].y, v[31].y);                                      \
        float m0 = fmaxf(max3f(max3f(t0[0], t0[1], t0[2]),                     \
                               max3f(t0[3], t0[4], t0[5]),                     \
                               max3f(t0[6], t0[7], t0[8])),                    \
                         fmaxf(t0[9], t0[10]));                                \
        float m1 = fmaxf(max3f(max3f(t1[0], t1[1], t1[2]),                     \
                               max3f(t1[3], t1[4], t1[5]),                     \
                               max3f(t1[6], t1[7], t1[8])),                    \
                         fmaxf(t1[9], t1[10]));                                \
        int s0 = 0, s1 = 0;                                                    \
        _Pragma("unroll") for (int s = KD - 1; s >= 0; --s) {                  \
            s0 = (v[s].x == m0) ? s : s0;                                      \
            s1 = (v[s].y == m1) ? s : s1;                                      \
        }                                                                      \
        const unsigned wm0 = 1u << s0, wm1 = 1u << s1;                         \
        _Pragma("unroll") for (int s = 0; s < KD; ++s) {                       \
            int id = ids[J][s];                                                \
            unsigned lose =                                                    \
                3u ^ (((wm0 >> s) & 1u) | (((wm1 >> s) & 1u) << 1));           \
            atomicOr(&fl[id >> 4], lose << ((id & 15) * 2));                   \
        }                                                                      \
    }

    // ---- explicit ping-pong pipeline: gather j+1 overlaps compute j ----
    GATHER(vA, 0)
    GATHER(vB, 1)
    COMPUTE(vA, 0)
    GATHER(vA, 2)
    COMPUTE(vB, 1)
    GATHER(vB, 3)
    COMPUTE(vA, 2)
    COMPUTE(vB, 3)

#undef GATHER
#undef COMPUTE

    __syncthreads();

    // pack: word tid covers inputs [16*tid, 16*tid+15]; compact even/odd bits
    unsigned f  = fl[tid];
    unsigned b0 = compact_even(f);
    unsigned b1 = compact_even(f >> 1);
    unsigned short* pm0 =
        (unsigned short*)(pm + ((size_t)(2 * pair) * SLICES + slice) * (N_INPUTS / 64));
    unsigned short* pm1 =
        (unsigned short*)(pm + ((size_t)(2 * pair + 1) * SLICES + slice) * (N_INPUTS / 64));
    pm0[tid] = (unsigned short)b0;
    pm1[tid] = (unsigned short)b1;
}

// ---------------------------------------------------------------------------
// out[b][i] = 1.0 iff bit i clear in OR of the batch's 16 slice masks.
// ---------------------------------------------------------------------------
__global__ __launch_bounds__(256) void finalize(const unsigned* __restrict__ pm,
                                                float* __restrict__ out) {
    const int gid = blockIdx.x * 256 + threadIdx.x;   // 0 .. B*N_INPUTS-1
    const int b   = gid >> 14;
    const int i   = gid & (N_INPUTS - 1);
    unsigned acc = 0;
#pragma unroll
    for (int s = 0; s < SLICES; ++s)
        acc |= pm[((b * SLICES + s) << 9) + (i >> 5)]; // 512 u32 per partial
    out[gid] = ((acc >> (i & 31)) & 1u) ? 0.0f : 1.0f;
}

extern "C" void kernel_launch(void* const* d_in, const int* in_sizes, int n_in,
                              void* d_out, int out_size, void* d_ws, size_t ws_size,
                              hipStream_t stream) {
    const float* x   = (const float*)d_in[0];              // [B, N_INPUTS] f32
    const int*   det = (const int*)d_in[1];                // [N_DET, K] i32
    unsigned long long* pm = (unsigned long long*)d_ws;    // 1 MB partial masks

    dim3 grid(SLICES, BATCH / 2);
    inhibit<<<grid, THREADS, 0, stream>>>(x, det, pm);
    finalize<<<BATCH * N_INPUTS / 256, 256, 0, stream>>>((const unsigned*)pm,
                                                         (float*)d_out);
}

// Round 5
// 86.479 us; speedup vs baseline: 2.2347x; 2.2347x over previous
//
#include <hip/hip_runtime.h>

#define N_INPUTS 16384
#define N_DET    65536
#define KD       32
#define BATCH    32
#define SLICES   16                        // det slices; slice -> fixed XCD
#define DPB      (N_DET / SLICES)          // 4096 detectors per block
#define THREADS  512                       // 8 waves, 1 block/CU (132 KB LDS)
                                           // -> 2 waves/SIMD -> 256 VGPR/wave

__device__ __forceinline__ float max3f(float a, float b, float c) {
    return fmaxf(fmaxf(a, b), c);          // fuses to v_max3_f32
}

// keep even bits of a 32-bit word -> 16-bit compaction
__device__ __forceinline__ unsigned compact_even(unsigned v) {
    v &= 0x55555555u;
    v = (v | (v >> 1)) & 0x33333333u;
    v = (v | (v >> 2)) & 0x0F0F0F0Fu;
    v = (v | (v >> 4)) & 0x00FF00FFu;
    v = (v | (v >> 8)) & 0x0000FFFFu;
    return v;
}

// ---------------------------------------------------------------------------
// Round-0 algorithm, reshaped for ILP within an honest register budget.
// R4 lesson: at 1024 thr/block the per-wave VGPR ceiling is 128 (4 waves/SIMD
// must fit), so any depth-2 pipeline spills (VGPR=64 + 350MB scratch traffic
// observed). At 512 thr/block the ceiling is 256: vA+vB (128) + idsE+idsO
// (64) + temps fits. Each thread owns 8 detectors as 4 software-pipelined
// pairs: gather(B) issues ahead of compute(A); next pair's id-rows load
// under the computes (~250cyc VALU covers L2 latency); the loop-carried
// gather(A) is one full COMPUTE away from its id load. All indices are
// compile-time (hand-unrolled pairs) -> no scratch.
// ---------------------------------------------------------------------------
__global__ __launch_bounds__(THREADS, 2) void inhibit(const float* __restrict__ x,
                                                      const int* __restrict__ det,
                                                      unsigned long long* __restrict__ pm) {
    __shared__ float2   xs[N_INPUTS];        // 128 KB: [id] -> (x_b0, x_b1)
    __shared__ unsigned fl[N_INPUTS / 16];   // 4 KB: bit 2p = b0-loser, 2p+1 = b1

    const int slice = blockIdx.x;
    const int pair  = blockIdx.y;
    const int tid   = threadIdx.x;

    fl[tid] = 0u;                            // 1024 words / 512 threads
    fl[tid + 512] = 0u;

    // stage both rows interleaved: xs[i] = (x[b0][i], x[b1][i])
    const float4* x0 = (const float4*)(x + (size_t)(2 * pair) * N_INPUTS);
    const float4* x1 = (const float4*)(x + (size_t)(2 * pair + 1) * N_INPUTS);
    float4* xs4 = (float4*)xs;
#pragma unroll
    for (int k = 0; k < N_INPUTS / 4 / THREADS; ++k) {
        int t = tid + k * THREADS;
        float4 a = x0[t], b = x1[t];
        xs4[2 * t + 0] = make_float4(a.x, b.x, a.y, b.y);
        xs4[2 * t + 1] = make_float4(a.z, b.z, a.w, b.w);
    }
    __syncthreads();

    const int4* det4 = (const int4*)det;
    int idsE[KD], idsO[KD];
    float2 vA[KD], vB[KD];

#define LOADIDS(dst, J)                                                        \
    {                                                                          \
        const int4* drow =                                                     \
            det4 + (size_t)(slice * DPB + (J) * THREADS + tid) * 8;            \
        _Pragma("unroll") for (int q = 0; q < 8; ++q) {                        \
            int4 r = drow[q];                                                  \
            dst[4 * q + 0] = r.x; dst[4 * q + 1] = r.y;                        \
            dst[4 * q + 2] = r.z; dst[4 * q + 3] = r.w;                        \
        }                                                                      \
    }

#define GATHER(vbuf, idb)                                                      \
    _Pragma("unroll") for (int s = 0; s < KD; ++s) vbuf[s] = xs[idb[s]];

#define COMPUTE(v, idb)                                                        \
    {                                                                          \
        float t0[11], t1[11];                                                  \
        _Pragma("unroll") for (int i = 0; i < 10; ++i) {                       \
            t0[i] = max3f(v[3 * i].x, v[3 * i + 1].x, v[3 * i + 2].x);         \
            t1[i] = max3f(v[3 * i].y, v[3 * i + 1].y, v[3 * i + 2].y);         \
        }                                                                      \
        t0[10] = fmaxf(v[30].x, v[31].x);                                      \
        t1[10] = fmaxf(v[30].y, v[31].y);                                      \
        float m0 = fmaxf(max3f(max3f(t0[0], t0[1], t0[2]),                     \
                               max3f(t0[3], t0[4], t0[5]),                     \
                               max3f(t0[6], t0[7], t0[8])),                    \
                         fmaxf(t0[9], t0[10]));                                \
        float m1 = fmaxf(max3f(max3f(t1[0], t1[1], t1[2]),                     \
                               max3f(t1[3], t1[4], t1[5]),                     \
                               max3f(t1[6], t1[7], t1[8])),                    \
                         fmaxf(t1[9], t1[10]));                                \
        int s0 = 0, s1 = 0;                                                    \
        _Pragma("unroll") for (int s = KD - 1; s >= 0; --s) {                  \
            s0 = (v[s].x == m0) ? s : s0;                                      \
            s1 = (v[s].y == m1) ? s : s1;                                      \
        }                                                                      \
        const unsigned wm0 = 1u << s0, wm1 = 1u << s1;                         \
        _Pragma("unroll") for (int s = 0; s < KD; ++s) {                       \
            int id = idb[s];                                                   \
            unsigned lose =                                                    \
                3u ^ (((wm0 >> s) & 1u) | (((wm1 >> s) & 1u) << 1));           \
            atomicOr(&fl[id >> 4], lose << ((id & 15) * 2));                   \
        }                                                                      \
    }

    // ---- prologue ----
    LOADIDS(idsE, 0)
    LOADIDS(idsO, 1)
    GATHER(vA, idsE)
    // ---- pair 0 (dets 0,1; prefetch 2,3) ----
    GATHER(vB, idsO)
    COMPUTE(vA, idsE)
    LOADIDS(idsE, 2)
    COMPUTE(vB, idsO)
    LOADIDS(idsO, 3)
    GATHER(vA, idsE)
    // ---- pair 1 (dets 2,3; prefetch 4,5) ----
    GATHER(vB, idsO)
    COMPUTE(vA, idsE)
    LOADIDS(idsE, 4)
    COMPUTE(vB, idsO)
    LOADIDS(idsO, 5)
    GATHER(vA, idsE)
    // ---- pair 2 (dets 4,5; prefetch 6,7) ----
    GATHER(vB, idsO)
    COMPUTE(vA, idsE)
    LOADIDS(idsE, 6)
    COMPUTE(vB, idsO)
    LOADIDS(idsO, 7)
    GATHER(vA, idsE)
    // ---- pair 3 (dets 6,7; no prefetch) ----
    GATHER(vB, idsO)
    COMPUTE(vA, idsE)
    COMPUTE(vB, idsO)

#undef LOADIDS
#undef GATHER
#undef COMPUTE

    __syncthreads();

    // pack: word w covers inputs [16w, 16w+15]; compact even/odd bits
    unsigned short* pm0 =
        (unsigned short*)(pm + ((size_t)(2 * pair) * SLICES + slice) * (N_INPUTS / 64));
    unsigned short* pm1 =
        (unsigned short*)(pm + ((size_t)(2 * pair + 1) * SLICES + slice) * (N_INPUTS / 64));
#pragma unroll
    for (int k = 0; k < 2; ++k) {
        int w = tid + k * 512;
        unsigned f = fl[w];
        pm0[w] = (unsigned short)compact_even(f);
        pm1[w] = (unsigned short)compact_even(f >> 1);
    }
}

// ---------------------------------------------------------------------------
// out[b][i] = 1.0 iff bit i clear in OR of the batch's 16 slice masks.
// ---------------------------------------------------------------------------
__global__ __launch_bounds__(256) void finalize(const unsigned* __restrict__ pm,
                                                float* __restrict__ out) {
    const int gid = blockIdx.x * 256 + threadIdx.x;   // 0 .. B*N_INPUTS-1
    const int b   = gid >> 14;
    const int i   = gid & (N_INPUTS - 1);
    unsigned acc = 0;
#pragma unroll
    for (int s = 0; s < SLICES; ++s)
        acc |= pm[((b * SLICES + s) << 9) + (i >> 5)]; // 512 u32 per partial
    out[gid] = ((acc >> (i & 31)) & 1u) ? 0.0f : 1.0f;
}

extern "C" void kernel_launch(void* const* d_in, const int* in_sizes, int n_in,
                              void* d_out, int out_size, void* d_ws, size_t ws_size,
                              hipStream_t stream) {
    const float* x   = (const float*)d_in[0];              // [B, N_INPUTS] f32
    const int*   det = (const int*)d_in[1];                // [N_DET, K] i32
    unsigned long long* pm = (unsigned long long*)d_ws;    // 1 MB partial masks

    dim3 grid(SLICES, BATCH / 2);
    inhibit<<<grid, THREADS, 0, stream>>>(x, det, pm);
    finalize<<<BATCH * N_INPUTS / 256, 256, 0, stream>>>((const unsigned*)pm,
                                                         (float*)d_out);
}